// Round 9
// baseline (47.982 us; speedup 1.0000x reference)
//
#include <hip/hip_runtime.h>
#include <math.h>

#define NB 32
#define NI 32
#define NA 16
#define NOD 10
#define NOA 16
#define NK 160         // NOD*NOA
#define NHW 144
#define NROUT 3
#define NROWS (NB*NHW) // 4608 pixel-rows
#define SVLD 168       // ushort row stride (336 B, uint4-aligned)

// workspace layout: [w_bf: 81920 ushort = 160KB][pad][x_t2: NROWS*512 f32]
#define XT_OFF 262144
#define WS_NEEDED (XT_OFF + (size_t)NROWS * 512 * 4)

// ---- bf16 RNE pack / unpack ----
__device__ __forceinline__ unsigned short f2bf(float f) {
    unsigned b = __builtin_bit_cast(unsigned, f);
    b += 0x7fffu + ((b >> 16) & 1u);
    return (unsigned short)(b >> 16);
}
__device__ __forceinline__ float bf_lo(unsigned d) {
    return __builtin_bit_cast(float, d << 16);
}
__device__ __forceinline__ float bf_hi(unsigned d) {
    return __builtin_bit_cast(float, d & 0xffff0000u);
}

// =====================================================================
// Pre-pass: (a) weight f32 -> bf16 (halves phase-1b L2 bytes & loads),
// (b) x -> x_t2[b][hw/4][i][a][hw%4] so each fused block reads its 8KB
// x-slice CONTIGUOUSLY (R8 read 16B float4s at stride 576B: 4x HBM
// overfetch, FETCH 37MB for a 12MB footprint).
// =====================================================================
__global__ __launch_bounds__(256)
void prepass_kernel(const float* __restrict__ x,       // [B, 512 j, 144 hw]
                    const float* __restrict__ weight,  // [81920]
                    unsigned short* __restrict__ w_bf,
                    float* __restrict__ x_t)           // [B][36][512][4]
{
    int bid = blockIdx.x;
    const int tid = threadIdx.x;
    if (bid < 320) {                       // weight: 320*256 = 81920
        const int idx = bid * 256 + tid;
        w_bf[idx] = f2bf(weight[idx]);
        return;
    }
    bid -= 320;                            // x transpose tiles
    const int b  = bid / 72;
    const int r  = bid % 72;
    const int jt = r / 9;                  // 8 j-tiles of 64
    const int ht = r % 9;                  // 9 hw-tiles of 16
    const int j0 = jt * 64, hw0 = ht * 16;

    __shared__ float tile[64][17];
    {
        const int hh = tid & 15;
        const int j1 = tid >> 4;           // 0..15
#pragma unroll
        for (int s = 0; s < 4; ++s) {
            const int jj = j1 + s * 16;
            tile[jj][hh] = x[(size_t)b * 73728 + (size_t)(j0 + jj) * NHW + hw0 + hh];
        }
    }
    __syncthreads();
    {
        const int jj = tid >> 2;           // 0..63
        const int p  = tid & 3;
#pragma unroll
        for (int s = 0; s < 4; ++s) {      // hwg_local = s
            const int hwg = ht * 4 + s;
            x_t[((size_t)b * 36 + hwg) * 2048 + (size_t)(j0 + jj) * 4 + p] =
                tile[jj][s * 4 + p];
        }
    }
}

// =====================================================================
// Fused kernel v2. Block = 256 thr = 4 waves = 4 pixel-rows.
// Phase 1: contiguous 8KB x load -> pool; votes with bf16 weight
//   (oct-tasks: one uint4 = 8 bf16 k-values, 40 loads/thread vs 80).
// Phase 2: wave-synchronous routing (R7/R8 proven, unchanged).
// =====================================================================
__global__ __launch_bounds__(256)
void capsule_fused2_kernel(const float* __restrict__ x_t,          // [NROWS/4][2048]
                           const unsigned short* __restrict__ w_bf,// [NI*NA*NK]
                           const float* __restrict__ bias,         // [NK]
                           float* __restrict__ out)                // [B,K,HW]
{
    __shared__ unsigned short sv[4][NI][SVLD];      // 43 KB bf16 votes
    __shared__ __align__(16) float pool[2048];      // 8 KB: sx | srt+sact
    float* const srt_f  = pool;                     // [4][NOD][33]
    float* const sact_f = pool + 4 * NOD * 33;      // [4][164]

    const int tid = threadIdx.x;
    const int w   = tid >> 6;
    const int l   = tid & 63;
    const int b   = blockIdx.x / (NHW / 4);
    const int hw0 = (blockIdx.x % (NHW / 4)) * 4;

    // ---- phase 1a: contiguous x slice -> pool ([i][a][p] layout) ----
    {
        const float4* src = reinterpret_cast<const float4*>(x_t + (size_t)blockIdx.x * 2048);
        float4* dst = reinterpret_cast<float4*>(pool);
        dst[tid]       = src[tid];
        dst[tid + 256] = src[tid + 256];
    }
    __syncthreads();

    // ---- phase 1b: votes. oct-task (i, k-oct): 640 tasks ----
    for (int t = tid; t < NI * 20; t += 256) {
        const int i  = t / 20;
        const int ko = t - i * 20;
        const int k0 = ko * 8;
        const uint4* wp = reinterpret_cast<const uint4*>(w_bf + (size_t)i * NA * NK + k0);
        float4 acc[4][2];
#pragma unroll
        for (int p = 0; p < 4; ++p) {
            acc[p][0] = make_float4(0.f, 0.f, 0.f, 0.f);
            acc[p][1] = make_float4(0.f, 0.f, 0.f, 0.f);
        }
#pragma unroll
        for (int a = 0; a < NA; ++a) {
            const uint4 wv = wp[(size_t)a * 20];    // 8 bf16 k-values
            const float w0 = bf_lo(wv.x), w1 = bf_hi(wv.x);
            const float w2 = bf_lo(wv.y), w3 = bf_hi(wv.y);
            const float w4 = bf_lo(wv.z), w5 = bf_hi(wv.z);
            const float w6 = bf_lo(wv.w), w7 = bf_hi(wv.w);
            const float4 xa = *reinterpret_cast<const float4*>(&pool[(i * NA + a) * 4]);
            const float xs[4] = {xa.x, xa.y, xa.z, xa.w};
#pragma unroll
            for (int p = 0; p < 4; ++p) {
                const float xv = xs[p];
                acc[p][0].x = fmaf(xv, w0, acc[p][0].x);
                acc[p][0].y = fmaf(xv, w1, acc[p][0].y);
                acc[p][0].z = fmaf(xv, w2, acc[p][0].z);
                acc[p][0].w = fmaf(xv, w3, acc[p][0].w);
                acc[p][1].x = fmaf(xv, w4, acc[p][1].x);
                acc[p][1].y = fmaf(xv, w5, acc[p][1].y);
                acc[p][1].z = fmaf(xv, w6, acc[p][1].z);
                acc[p][1].w = fmaf(xv, w7, acc[p][1].w);
            }
        }
#pragma unroll
        for (int p = 0; p < 4; ++p) {
            *reinterpret_cast<ushort4*>(&sv[p][i][k0]) =
                make_ushort4(f2bf(acc[p][0].x), f2bf(acc[p][0].y),
                             f2bf(acc[p][0].z), f2bf(acc[p][0].w));
            *reinterpret_cast<ushort4*>(&sv[p][i][k0 + 4]) =
                make_ushort4(f2bf(acc[p][1].x), f2bf(acc[p][1].y),
                             f2bf(acc[p][1].z), f2bf(acc[p][1].w));
        }
    }

    // bias in registers (pair layout matches preact lane map)
    const float2 b0 = *reinterpret_cast<const float2*>(bias + 2 * l);
    float2 b1 = make_float2(0.f, 0.f);
    if (l < 16) b1 = *reinterpret_cast<const float2*>(bias + 128 + 2 * l);

    float lg[NOD];
#pragma unroll
    for (int od = 0; od < NOD; ++od) lg[od] = 0.f;
    const int iown = l & 31;

    __syncthreads();   // sv complete; pool free for srt/sact

    // ---- phase 2: wave-synchronous routing ----
    for (int it = 0; it < NROUT; ++it) {
        {
            float m = lg[0];
#pragma unroll
            for (int od = 1; od < NOD; ++od) m = fmaxf(m, lg[od]);
            float e[NOD];
            float s = 0.f;
#pragma unroll
            for (int od = 0; od < NOD; ++od) {
                e[od] = __expf(lg[od] - m);
                s += e[od];
            }
            const float inv = 1.f / s;
            if (l < 32) {
#pragma unroll
                for (int od = 0; od < NOD; ++od)
                    srt_f[(w * NOD + od) * 33 + iown] = e[od] * inv;
            }
        }
        __builtin_amdgcn_wave_barrier();

        {
            const int od0 = l >> 3;                  // rep0: k0 = 2l
            float a0 = b0.x, a1 = b0.y;
#pragma unroll
            for (int i = 0; i < NI; ++i) {
                const unsigned d = *reinterpret_cast<const unsigned*>(&sv[w][i][2 * l]);
                const float r = srt_f[(w * NOD + od0) * 33 + i];
                a0 = fmaf(r, bf_lo(d), a0);
                a1 = fmaf(r, bf_hi(d), a1);
            }
            float ss = a0 * a0 + a1 * a1;
            ss += __shfl_xor(ss, 1, 8);
            ss += __shfl_xor(ss, 2, 8);
            ss += __shfl_xor(ss, 4, 8);
            const float sc = sqrtf(ss) / (1.f + ss);
            *reinterpret_cast<float2*>(&sact_f[w * 164 + 2 * l]) =
                make_float2(a0 * sc, a1 * sc);

            if (l < 16) {                            // rep1: k0 = 128 + 2l
                const int od1 = 8 + (l >> 3);
                float c0 = b1.x, c1 = b1.y;
#pragma unroll
                for (int i = 0; i < NI; ++i) {
                    const unsigned d = *reinterpret_cast<const unsigned*>(&sv[w][i][128 + 2 * l]);
                    const float r = srt_f[(w * NOD + od1) * 33 + i];
                    c0 = fmaf(r, bf_lo(d), c0);
                    c1 = fmaf(r, bf_hi(d), c1);
                }
                float s2 = c0 * c0 + c1 * c1;
                s2 += __shfl_xor(s2, 1, 8);
                s2 += __shfl_xor(s2, 2, 8);
                s2 += __shfl_xor(s2, 4, 8);
                const float sc2 = sqrtf(s2) / (1.f + s2);
                *reinterpret_cast<float2*>(&sact_f[w * 164 + 128 + 2 * l]) =
                    make_float2(c0 * sc2, c1 * sc2);
            }
        }
        __builtin_amdgcn_wave_barrier();

        if (it < NROUT - 1) {
#pragma unroll
            for (int r = 0; r < 5; ++r) {
                const int t  = l + 64 * r;
                const int i  = t & 31;
                const int od = t >> 5;
                const uint4 d0 = *reinterpret_cast<const uint4*>(&sv[w][i][od * NOA]);
                const uint4 d1 = *reinterpret_cast<const uint4*>(&sv[w][i][od * NOA + 8]);
                const float* ap = &sact_f[w * 164 + od * NOA];
                const float4 c0 = *reinterpret_cast<const float4*>(ap + 0);
                const float4 c1 = *reinterpret_cast<const float4*>(ap + 4);
                const float4 c2 = *reinterpret_cast<const float4*>(ap + 8);
                const float4 c3 = *reinterpret_cast<const float4*>(ap + 12);
                float acc;
                acc  = bf_lo(d0.x) * c0.x;
                acc = fmaf(bf_hi(d0.x), c0.y, acc);
                acc = fmaf(bf_lo(d0.y), c0.z, acc);
                acc = fmaf(bf_hi(d0.y), c0.w, acc);
                acc = fmaf(bf_lo(d0.z), c1.x, acc);
                acc = fmaf(bf_hi(d0.z), c1.y, acc);
                acc = fmaf(bf_lo(d0.w), c1.z, acc);
                acc = fmaf(bf_hi(d0.w), c1.w, acc);
                acc = fmaf(bf_lo(d1.x), c2.x, acc);
                acc = fmaf(bf_hi(d1.x), c2.y, acc);
                acc = fmaf(bf_lo(d1.y), c2.z, acc);
                acc = fmaf(bf_hi(d1.y), c2.w, acc);
                acc = fmaf(bf_lo(d1.z), c3.x, acc);
                acc = fmaf(bf_hi(d1.z), c3.y, acc);
                acc = fmaf(bf_lo(d1.w), c3.z, acc);
                acc = fmaf(bf_hi(d1.w), c3.w, acc);
                srt_f[(w * NOD + od) * 33 + i] = acc;
            }
            __builtin_amdgcn_wave_barrier();
#pragma unroll
            for (int od = 0; od < NOD; ++od)
                lg[od] += srt_f[(w * NOD + od) * 33 + iown];
            __builtin_amdgcn_wave_barrier();
        }
    }

    // ---- output: float4 across the block's 4 consecutive pixels ----
    __syncthreads();
    if (tid < NK) {
        const float4 v = make_float4(sact_f[0 * 164 + tid], sact_f[1 * 164 + tid],
                                     sact_f[2 * 164 + tid], sact_f[3 * 164 + tid]);
        *reinterpret_cast<float4*>(out + ((size_t)b * NK + tid) * NHW + hw0) = v;
    }
}

// =====================================================================
// Fallback: R8 fused kernel (f32 weight, direct x read) if ws too small.
// =====================================================================
__global__ __launch_bounds__(256)
void capsule_fused_kernel(const float* __restrict__ x,
                          const float* __restrict__ weight,
                          const float* __restrict__ bias,
                          float* __restrict__ out)
{
    __shared__ unsigned short sv[4][NI][SVLD];
    __shared__ __align__(16) float pool[2048];
    float* const srt_f  = pool;
    float* const sact_f = pool + 4 * NOD * 33;

    const int tid = threadIdx.x;
    const int w   = tid >> 6;
    const int l   = tid & 63;
    const int b   = blockIdx.x / (NHW / 4);
    const int hw0 = (blockIdx.x % (NHW / 4)) * 4;

    {
        const float* xb = x + ((size_t)b * NI * NA) * NHW + hw0;
        for (int j = tid; j < NI * NA; j += 256) {
            const float4 v = *reinterpret_cast<const float4*>(xb + (size_t)j * NHW);
            *reinterpret_cast<float4*>(&pool[j * 4]) = v;
        }
    }
    __syncthreads();

    for (int j = tid; j < NI * 40; j += 256) {
        const int i  = j / 40;
        const int kq = j - i * 40;
        const int k0 = kq * 4;
        const float4* wp = reinterpret_cast<const float4*>(weight + (size_t)i * NA * NK + k0);
        float4 a0 = make_float4(0.f,0.f,0.f,0.f), a1 = a0, a2 = a0, a3 = a0;
#pragma unroll
        for (int a = 0; a < NA; ++a) {
            const float4 w4 = wp[(size_t)a * 40];
            const float4 xa = *reinterpret_cast<const float4*>(&pool[(i * NA + a) * 4]);
            a0.x = fmaf(xa.x, w4.x, a0.x); a0.y = fmaf(xa.x, w4.y, a0.y);
            a0.z = fmaf(xa.x, w4.z, a0.z); a0.w = fmaf(xa.x, w4.w, a0.w);
            a1.x = fmaf(xa.y, w4.x, a1.x); a1.y = fmaf(xa.y, w4.y, a1.y);
            a1.z = fmaf(xa.y, w4.z, a1.z); a1.w = fmaf(xa.y, w4.w, a1.w);
            a2.x = fmaf(xa.z, w4.x, a2.x); a2.y = fmaf(xa.z, w4.y, a2.y);
            a2.z = fmaf(xa.z, w4.z, a2.z); a2.w = fmaf(xa.z, w4.w, a2.w);
            a3.x = fmaf(xa.w, w4.x, a3.x); a3.y = fmaf(xa.w, w4.y, a3.y);
            a3.z = fmaf(xa.w, w4.z, a3.z); a3.w = fmaf(xa.w, w4.w, a3.w);
        }
        *reinterpret_cast<ushort4*>(&sv[0][i][k0]) =
            make_ushort4(f2bf(a0.x), f2bf(a0.y), f2bf(a0.z), f2bf(a0.w));
        *reinterpret_cast<ushort4*>(&sv[1][i][k0]) =
            make_ushort4(f2bf(a1.x), f2bf(a1.y), f2bf(a1.z), f2bf(a1.w));
        *reinterpret_cast<ushort4*>(&sv[2][i][k0]) =
            make_ushort4(f2bf(a2.x), f2bf(a2.y), f2bf(a2.z), f2bf(a2.w));
        *reinterpret_cast<ushort4*>(&sv[3][i][k0]) =
            make_ushort4(f2bf(a3.x), f2bf(a3.y), f2bf(a3.z), f2bf(a3.w));
    }

    const float2 b0 = *reinterpret_cast<const float2*>(bias + 2 * l);
    float2 b1 = make_float2(0.f, 0.f);
    if (l < 16) b1 = *reinterpret_cast<const float2*>(bias + 128 + 2 * l);

    float lg[NOD];
#pragma unroll
    for (int od = 0; od < NOD; ++od) lg[od] = 0.f;
    const int iown = l & 31;

    __syncthreads();

    for (int it = 0; it < NROUT; ++it) {
        {
            float m = lg[0];
#pragma unroll
            for (int od = 1; od < NOD; ++od) m = fmaxf(m, lg[od]);
            float e[NOD];
            float s = 0.f;
#pragma unroll
            for (int od = 0; od < NOD; ++od) { e[od] = __expf(lg[od] - m); s += e[od]; }
            const float inv = 1.f / s;
            if (l < 32) {
#pragma unroll
                for (int od = 0; od < NOD; ++od)
                    srt_f[(w * NOD + od) * 33 + iown] = e[od] * inv;
            }
        }
        __builtin_amdgcn_wave_barrier();
        {
            const int od0 = l >> 3;
            float a0 = b0.x, a1 = b0.y;
#pragma unroll
            for (int i = 0; i < NI; ++i) {
                const unsigned d = *reinterpret_cast<const unsigned*>(&sv[w][i][2 * l]);
                const float r = srt_f[(w * NOD + od0) * 33 + i];
                a0 = fmaf(r, bf_lo(d), a0);
                a1 = fmaf(r, bf_hi(d), a1);
            }
            float ss = a0 * a0 + a1 * a1;
            ss += __shfl_xor(ss, 1, 8);
            ss += __shfl_xor(ss, 2, 8);
            ss += __shfl_xor(ss, 4, 8);
            const float sc = sqrtf(ss) / (1.f + ss);
            *reinterpret_cast<float2*>(&sact_f[w * 164 + 2 * l]) = make_float2(a0 * sc, a1 * sc);
            if (l < 16) {
                const int od1 = 8 + (l >> 3);
                float c0 = b1.x, c1 = b1.y;
#pragma unroll
                for (int i = 0; i < NI; ++i) {
                    const unsigned d = *reinterpret_cast<const unsigned*>(&sv[w][i][128 + 2 * l]);
                    const float r = srt_f[(w * NOD + od1) * 33 + i];
                    c0 = fmaf(r, bf_lo(d), c0);
                    c1 = fmaf(r, bf_hi(d), c1);
                }
                float s2 = c0 * c0 + c1 * c1;
                s2 += __shfl_xor(s2, 1, 8);
                s2 += __shfl_xor(s2, 2, 8);
                s2 += __shfl_xor(s2, 4, 8);
                const float sc2 = sqrtf(s2) / (1.f + s2);
                *reinterpret_cast<float2*>(&sact_f[w * 164 + 128 + 2 * l]) =
                    make_float2(c0 * sc2, c1 * sc2);
            }
        }
        __builtin_amdgcn_wave_barrier();
        if (it < NROUT - 1) {
#pragma unroll
            for (int r = 0; r < 5; ++r) {
                const int t  = l + 64 * r;
                const int i  = t & 31;
                const int od = t >> 5;
                const uint4 d0 = *reinterpret_cast<const uint4*>(&sv[w][i][od * NOA]);
                const uint4 d1 = *reinterpret_cast<const uint4*>(&sv[w][i][od * NOA + 8]);
                const float* ap = &sact_f[w * 164 + od * NOA];
                const float4 c0 = *reinterpret_cast<const float4*>(ap + 0);
                const float4 c1 = *reinterpret_cast<const float4*>(ap + 4);
                const float4 c2 = *reinterpret_cast<const float4*>(ap + 8);
                const float4 c3 = *reinterpret_cast<const float4*>(ap + 12);
                float acc;
                acc  = bf_lo(d0.x) * c0.x;
                acc = fmaf(bf_hi(d0.x), c0.y, acc);
                acc = fmaf(bf_lo(d0.y), c0.z, acc);
                acc = fmaf(bf_hi(d0.y), c0.w, acc);
                acc = fmaf(bf_lo(d0.z), c1.x, acc);
                acc = fmaf(bf_hi(d0.z), c1.y, acc);
                acc = fmaf(bf_lo(d0.w), c1.z, acc);
                acc = fmaf(bf_hi(d0.w), c1.w, acc);
                acc = fmaf(bf_lo(d1.x), c2.x, acc);
                acc = fmaf(bf_hi(d1.x), c2.y, acc);
                acc = fmaf(bf_lo(d1.y), c2.z, acc);
                acc = fmaf(bf_hi(d1.y), c2.w, acc);
                acc = fmaf(bf_lo(d1.z), c3.x, acc);
                acc = fmaf(bf_hi(d1.z), c3.y, acc);
                acc = fmaf(bf_lo(d1.w), c3.z, acc);
                acc = fmaf(bf_hi(d1.w), c3.w, acc);
                srt_f[(w * NOD + od) * 33 + i] = acc;
            }
            __builtin_amdgcn_wave_barrier();
#pragma unroll
            for (int od = 0; od < NOD; ++od)
                lg[od] += srt_f[(w * NOD + od) * 33 + iown];
            __builtin_amdgcn_wave_barrier();
        }
    }

    __syncthreads();
    if (tid < NK) {
        const float4 v = make_float4(sact_f[0 * 164 + tid], sact_f[1 * 164 + tid],
                                     sact_f[2 * 164 + tid], sact_f[3 * 164 + tid]);
        *reinterpret_cast<float4*>(out + ((size_t)b * NK + tid) * NHW + hw0) = v;
    }
}

extern "C" void kernel_launch(void* const* d_in, const int* in_sizes, int n_in,
                              void* d_out, int out_size, void* d_ws, size_t ws_size,
                              hipStream_t stream) {
    const float* x      = (const float*)d_in[0];
    const float* weight = (const float*)d_in[1];
    const float* bias   = (const float*)d_in[2];
    float* out          = (float*)d_out;

    if (ws_size >= WS_NEEDED) {
        unsigned short* w_bf = (unsigned short*)d_ws;
        float* x_t = (float*)((char*)d_ws + XT_OFF);
        prepass_kernel<<<320 + NB * 72, 256, 0, stream>>>(x, weight, w_bf, x_t);
        capsule_fused2_kernel<<<NROWS / 4, 256, 0, stream>>>(x_t, w_bf, bias, out);
    } else {
        capsule_fused_kernel<<<NROWS / 4, 256, 0, stream>>>(x, weight, bias, out);
    }
}

// Round 10
// 45.531 us; speedup vs baseline: 1.0538x; 1.0538x over previous
//
#include <hip/hip_runtime.h>
#include <math.h>

#define NB 32
#define NI 32
#define NA 16
#define NOD 10
#define NOA 16
#define NK 160         // NOD*NOA
#define NHW 144
#define NROUT 3
#define NROWS (NB*NHW) // 4608 pixel-rows
#define SVLD 168       // ushort row stride (336 B, uint4/b64-aligned)
#define SRTLD 34       // srt row stride (f32), 8B-aligned pairs, bank-spread

// workspace layout: [w_bf: 81920 ushort = 160KB][pad][x_t: NROWS*512 f32]
#define XT_OFF 262144
#define WS_NEEDED (XT_OFF + (size_t)NROWS * 512 * 4)

// ---- bf16 RNE pack / unpack ----
__device__ __forceinline__ unsigned short f2bf(float f) {
    unsigned b = __builtin_bit_cast(unsigned, f);
    b += 0x7fffu + ((b >> 16) & 1u);
    return (unsigned short)(b >> 16);
}
__device__ __forceinline__ float bf_lo(unsigned d) {
    return __builtin_bit_cast(float, d << 16);
}
__device__ __forceinline__ float bf_hi(unsigned d) {
    return __builtin_bit_cast(float, d & 0xffff0000u);
}

// =====================================================================
// Pre-pass (unchanged from R9): weight f32->bf16; x -> per-block-
// contiguous x_t[b][hw/4][i][a][hw%4] (kills the 4x HBM overfetch).
// =====================================================================
__global__ __launch_bounds__(256)
void prepass_kernel(const float* __restrict__ x,       // [B, 512 j, 144 hw]
                    const float* __restrict__ weight,  // [81920]
                    unsigned short* __restrict__ w_bf,
                    float* __restrict__ x_t)           // [B][36][512][4]
{
    int bid = blockIdx.x;
    const int tid = threadIdx.x;
    if (bid < 320) {                       // weight: 320*256 = 81920
        const int idx = bid * 256 + tid;
        w_bf[idx] = f2bf(weight[idx]);
        return;
    }
    bid -= 320;                            // x transpose tiles
    const int b  = bid / 72;
    const int r  = bid % 72;
    const int jt = r / 9;
    const int ht = r % 9;
    const int j0 = jt * 64, hw0 = ht * 16;

    __shared__ float tile[64][17];
    {
        const int hh = tid & 15;
        const int j1 = tid >> 4;
#pragma unroll
        for (int s = 0; s < 4; ++s) {
            const int jj = j1 + s * 16;
            tile[jj][hh] = x[(size_t)b * 73728 + (size_t)(j0 + jj) * NHW + hw0 + hh];
        }
    }
    __syncthreads();
    {
        const int jj = tid >> 2;
        const int p  = tid & 3;
#pragma unroll
        for (int s = 0; s < 4; ++s) {
            const int hwg = ht * 4 + s;
            x_t[((size_t)b * 36 + hwg) * 2048 + (size_t)(j0 + jj) * 4 + p] =
                tile[jj][s * 4 + p];
        }
    }
}

// =====================================================================
// Fused kernel v3. Block = 256 thr = 4 waves = 4 pixel-rows.
// Phase 1 unchanged from R9. Phase 2 routing reworked to cut LDS
// instruction count ~2.5x (R9 diagnosis: routing is LDS-issue-bound):
//   preact = k-QUAD per lane (40 lanes), sv read b64, srt read b64
//   over i-pairs -> 48 LDS instr/wave/iter vs 128.
// =====================================================================
__global__ __launch_bounds__(256)
void capsule_fused3_kernel(const float* __restrict__ x_t,          // [NROWS/4][2048]
                           const unsigned short* __restrict__ w_bf,// [NI*NA*NK]
                           const float* __restrict__ bias,         // [NK]
                           float* __restrict__ out)                // [B,K,HW]
{
    __shared__ unsigned short sv[4][NI][SVLD];      // 43 KB bf16 votes
    __shared__ __align__(16) float pool[2048];      // 8 KB: sx | srt+sact
    float* const srt_f  = pool;                     // [4][NOD][SRTLD] = 1360 f
    float* const sact_f = pool + 4 * NOD * SRTLD;   // [4][164] = 656 f

    const int tid = threadIdx.x;
    const int w   = tid >> 6;
    const int l   = tid & 63;
    const int b   = blockIdx.x / (NHW / 4);
    const int hw0 = (blockIdx.x % (NHW / 4)) * 4;

    // ---- phase 1a: contiguous x slice -> pool ([i][a][p] layout) ----
    {
        const float4* src = reinterpret_cast<const float4*>(x_t + (size_t)blockIdx.x * 2048);
        float4* dst = reinterpret_cast<float4*>(pool);
        dst[tid]       = src[tid];
        dst[tid + 256] = src[tid + 256];
    }
    __syncthreads();

    // ---- phase 1b: votes. oct-task (i, k-oct): 640 tasks ----
    for (int t = tid; t < NI * 20; t += 256) {
        const int i  = t / 20;
        const int ko = t - i * 20;
        const int k0 = ko * 8;
        const uint4* wp = reinterpret_cast<const uint4*>(w_bf + (size_t)i * NA * NK + k0);
        float4 acc[4][2];
#pragma unroll
        for (int p = 0; p < 4; ++p) {
            acc[p][0] = make_float4(0.f, 0.f, 0.f, 0.f);
            acc[p][1] = make_float4(0.f, 0.f, 0.f, 0.f);
        }
#pragma unroll
        for (int a = 0; a < NA; ++a) {
            const uint4 wv = wp[(size_t)a * 20];
            const float w0 = bf_lo(wv.x), w1 = bf_hi(wv.x);
            const float w2 = bf_lo(wv.y), w3 = bf_hi(wv.y);
            const float w4 = bf_lo(wv.z), w5 = bf_hi(wv.z);
            const float w6 = bf_lo(wv.w), w7 = bf_hi(wv.w);
            const float4 xa = *reinterpret_cast<const float4*>(&pool[(i * NA + a) * 4]);
            const float xs[4] = {xa.x, xa.y, xa.z, xa.w};
#pragma unroll
            for (int p = 0; p < 4; ++p) {
                const float xv = xs[p];
                acc[p][0].x = fmaf(xv, w0, acc[p][0].x);
                acc[p][0].y = fmaf(xv, w1, acc[p][0].y);
                acc[p][0].z = fmaf(xv, w2, acc[p][0].z);
                acc[p][0].w = fmaf(xv, w3, acc[p][0].w);
                acc[p][1].x = fmaf(xv, w4, acc[p][1].x);
                acc[p][1].y = fmaf(xv, w5, acc[p][1].y);
                acc[p][1].z = fmaf(xv, w6, acc[p][1].z);
                acc[p][1].w = fmaf(xv, w7, acc[p][1].w);
            }
        }
#pragma unroll
        for (int p = 0; p < 4; ++p) {
            *reinterpret_cast<ushort4*>(&sv[p][i][k0]) =
                make_ushort4(f2bf(acc[p][0].x), f2bf(acc[p][0].y),
                             f2bf(acc[p][0].z), f2bf(acc[p][0].w));
            *reinterpret_cast<ushort4*>(&sv[p][i][k0 + 4]) =
                make_ushort4(f2bf(acc[p][1].x), f2bf(acc[p][1].y),
                             f2bf(acc[p][1].z), f2bf(acc[p][1].w));
        }
    }

    // bias quad in registers (matches new preact lane map, l<40)
    float4 bq = make_float4(0.f, 0.f, 0.f, 0.f);
    if (l < 40) bq = *reinterpret_cast<const float4*>(bias + 4 * l);

    float lg[NOD];
#pragma unroll
    for (int od = 0; od < NOD; ++od) lg[od] = 0.f;
    const int iown = l & 31;

    __syncthreads();   // sv complete; pool free for srt/sact

    // ---- phase 2: wave-synchronous routing ----
    for (int it = 0; it < NROUT; ++it) {
        // softmax over od (redundant on both lane-halves; lanes<32 write)
        {
            float m = lg[0];
#pragma unroll
            for (int od = 1; od < NOD; ++od) m = fmaxf(m, lg[od]);
            float e[NOD];
            float s = 0.f;
#pragma unroll
            for (int od = 0; od < NOD; ++od) {
                e[od] = __expf(lg[od] - m);
                s += e[od];
            }
            const float inv = 1.f / s;
            if (l < 32) {
#pragma unroll
                for (int od = 0; od < NOD; ++od)
                    srt_f[(w * NOD + od) * SRTLD + iown] = e[od] * inv;
            }
        }
        __builtin_amdgcn_wave_barrier();

        // preact + squash: k-QUAD per lane (l<40), b64 sv + paired srt
        if (l < 40) {
            const int k0 = 4 * l;
            const int od = l >> 2;
            float a0 = bq.x, a1 = bq.y, a2 = bq.z, a3 = bq.w;
            const float* srow = &srt_f[(w * NOD + od) * SRTLD];
#pragma unroll
            for (int i = 0; i < NI; i += 2) {
                const float2 r2 = *reinterpret_cast<const float2*>(srow + i);
                const uint2 d0 = *reinterpret_cast<const uint2*>(&sv[w][i][k0]);
                const uint2 d1 = *reinterpret_cast<const uint2*>(&sv[w][i + 1][k0]);
                a0 = fmaf(r2.x, bf_lo(d0.x), a0);
                a1 = fmaf(r2.x, bf_hi(d0.x), a1);
                a2 = fmaf(r2.x, bf_lo(d0.y), a2);
                a3 = fmaf(r2.x, bf_hi(d0.y), a3);
                a0 = fmaf(r2.y, bf_lo(d1.x), a0);
                a1 = fmaf(r2.y, bf_hi(d1.x), a1);
                a2 = fmaf(r2.y, bf_lo(d1.y), a2);
                a3 = fmaf(r2.y, bf_hi(d1.y), a3);
            }
            float ss = a0 * a0 + a1 * a1 + a2 * a2 + a3 * a3;
            ss += __shfl_xor(ss, 1, 4);
            ss += __shfl_xor(ss, 2, 4);
            const float sc = sqrtf(ss) / (1.f + ss);
            *reinterpret_cast<float4*>(&sact_f[w * 164 + k0]) =
                make_float4(a0 * sc, a1 * sc, a2 * sc, a3 * sc);
        }
        __builtin_amdgcn_wave_barrier();

        if (it < NROUT - 1) {
            // agreement: 320 (i,od) tasks, 5 per lane
#pragma unroll
            for (int r = 0; r < 5; ++r) {
                const int t  = l + 64 * r;
                const int i  = t & 31;
                const int od = t >> 5;
                const uint4 d0 = *reinterpret_cast<const uint4*>(&sv[w][i][od * NOA]);
                const uint4 d1 = *reinterpret_cast<const uint4*>(&sv[w][i][od * NOA + 8]);
                const float* ap = &sact_f[w * 164 + od * NOA];
                const float4 c0 = *reinterpret_cast<const float4*>(ap + 0);
                const float4 c1 = *reinterpret_cast<const float4*>(ap + 4);
                const float4 c2 = *reinterpret_cast<const float4*>(ap + 8);
                const float4 c3 = *reinterpret_cast<const float4*>(ap + 12);
                float acc;
                acc  = bf_lo(d0.x) * c0.x;
                acc = fmaf(bf_hi(d0.x), c0.y, acc);
                acc = fmaf(bf_lo(d0.y), c0.z, acc);
                acc = fmaf(bf_hi(d0.y), c0.w, acc);
                acc = fmaf(bf_lo(d0.z), c1.x, acc);
                acc = fmaf(bf_hi(d0.z), c1.y, acc);
                acc = fmaf(bf_lo(d0.w), c1.z, acc);
                acc = fmaf(bf_hi(d0.w), c1.w, acc);
                acc = fmaf(bf_lo(d1.x), c2.x, acc);
                acc = fmaf(bf_hi(d1.x), c2.y, acc);
                acc = fmaf(bf_lo(d1.y), c2.z, acc);
                acc = fmaf(bf_hi(d1.y), c2.w, acc);
                acc = fmaf(bf_lo(d1.z), c3.x, acc);
                acc = fmaf(bf_hi(d1.z), c3.y, acc);
                acc = fmaf(bf_lo(d1.w), c3.z, acc);
                acc = fmaf(bf_hi(d1.w), c3.w, acc);
                srt_f[(w * NOD + od) * SRTLD + i] = acc;
            }
            __builtin_amdgcn_wave_barrier();
#pragma unroll
            for (int od = 0; od < NOD; ++od)
                lg[od] += srt_f[(w * NOD + od) * SRTLD + iown];
            __builtin_amdgcn_wave_barrier();
        }
    }

    // ---- output: float4 across the block's 4 consecutive pixels ----
    __syncthreads();
    if (tid < NK) {
        const float4 v = make_float4(sact_f[0 * 164 + tid], sact_f[1 * 164 + tid],
                                     sact_f[2 * 164 + tid], sact_f[3 * 164 + tid]);
        *reinterpret_cast<float4*>(out + ((size_t)b * NK + tid) * NHW + hw0) = v;
    }
}

// =====================================================================
// Fallback: R8 fused kernel (f32 weight, direct x read) if ws too small.
// =====================================================================
__global__ __launch_bounds__(256)
void capsule_fused_kernel(const float* __restrict__ x,
                          const float* __restrict__ weight,
                          const float* __restrict__ bias,
                          float* __restrict__ out)
{
    __shared__ unsigned short sv[4][NI][SVLD];
    __shared__ __align__(16) float pool[2048];
    float* const srt_f  = pool;
    float* const sact_f = pool + 4 * NOD * 33;

    const int tid = threadIdx.x;
    const int w   = tid >> 6;
    const int l   = tid & 63;
    const int b   = blockIdx.x / (NHW / 4);
    const int hw0 = (blockIdx.x % (NHW / 4)) * 4;

    {
        const float* xb = x + ((size_t)b * NI * NA) * NHW + hw0;
        for (int j = tid; j < NI * NA; j += 256) {
            const float4 v = *reinterpret_cast<const float4*>(xb + (size_t)j * NHW);
            *reinterpret_cast<float4*>(&pool[j * 4]) = v;
        }
    }
    __syncthreads();

    for (int j = tid; j < NI * 40; j += 256) {
        const int i  = j / 40;
        const int kq = j - i * 40;
        const int k0 = kq * 4;
        const float4* wp = reinterpret_cast<const float4*>(weight + (size_t)i * NA * NK + k0);
        float4 a0 = make_float4(0.f,0.f,0.f,0.f), a1 = a0, a2 = a0, a3 = a0;
#pragma unroll
        for (int a = 0; a < NA; ++a) {
            const float4 w4 = wp[(size_t)a * 40];
            const float4 xa = *reinterpret_cast<const float4*>(&pool[(i * NA + a) * 4]);
            a0.x = fmaf(xa.x, w4.x, a0.x); a0.y = fmaf(xa.x, w4.y, a0.y);
            a0.z = fmaf(xa.x, w4.z, a0.z); a0.w = fmaf(xa.x, w4.w, a0.w);
            a1.x = fmaf(xa.y, w4.x, a1.x); a1.y = fmaf(xa.y, w4.y, a1.y);
            a1.z = fmaf(xa.y, w4.z, a1.z); a1.w = fmaf(xa.y, w4.w, a1.w);
            a2.x = fmaf(xa.z, w4.x, a2.x); a2.y = fmaf(xa.z, w4.y, a2.y);
            a2.z = fmaf(xa.z, w4.z, a2.z); a2.w = fmaf(xa.z, w4.w, a2.w);
            a3.x = fmaf(xa.w, w4.x, a3.x); a3.y = fmaf(xa.w, w4.y, a3.y);
            a3.z = fmaf(xa.w, w4.z, a3.z); a3.w = fmaf(xa.w, w4.w, a3.w);
        }
        *reinterpret_cast<ushort4*>(&sv[0][i][k0]) =
            make_ushort4(f2bf(a0.x), f2bf(a0.y), f2bf(a0.z), f2bf(a0.w));
        *reinterpret_cast<ushort4*>(&sv[1][i][k0]) =
            make_ushort4(f2bf(a1.x), f2bf(a1.y), f2bf(a1.z), f2bf(a1.w));
        *reinterpret_cast<ushort4*>(&sv[2][i][k0]) =
            make_ushort4(f2bf(a2.x), f2bf(a2.y), f2bf(a2.z), f2bf(a2.w));
        *reinterpret_cast<ushort4*>(&sv[3][i][k0]) =
            make_ushort4(f2bf(a3.x), f2bf(a3.y), f2bf(a3.z), f2bf(a3.w));
    }

    const float2 b0 = *reinterpret_cast<const float2*>(bias + 2 * l);
    float2 b1 = make_float2(0.f, 0.f);
    if (l < 16) b1 = *reinterpret_cast<const float2*>(bias + 128 + 2 * l);

    float lg[NOD];
#pragma unroll
    for (int od = 0; od < NOD; ++od) lg[od] = 0.f;
    const int iown = l & 31;

    __syncthreads();

    for (int it = 0; it < NROUT; ++it) {
        {
            float m = lg[0];
#pragma unroll
            for (int od = 1; od < NOD; ++od) m = fmaxf(m, lg[od]);
            float e[NOD];
            float s = 0.f;
#pragma unroll
            for (int od = 0; od < NOD; ++od) { e[od] = __expf(lg[od] - m); s += e[od]; }
            const float inv = 1.f / s;
            if (l < 32) {
#pragma unroll
                for (int od = 0; od < NOD; ++od)
                    srt_f[(w * NOD + od) * 33 + iown] = e[od] * inv;
            }
        }
        __builtin_amdgcn_wave_barrier();
        {
            const int od0 = l >> 3;
            float a0 = b0.x, a1 = b0.y;
#pragma unroll
            for (int i = 0; i < NI; ++i) {
                const unsigned d = *reinterpret_cast<const unsigned*>(&sv[w][i][2 * l]);
                const float r = srt_f[(w * NOD + od0) * 33 + i];
                a0 = fmaf(r, bf_lo(d), a0);
                a1 = fmaf(r, bf_hi(d), a1);
            }
            float ss = a0 * a0 + a1 * a1;
            ss += __shfl_xor(ss, 1, 8);
            ss += __shfl_xor(ss, 2, 8);
            ss += __shfl_xor(ss, 4, 8);
            const float sc = sqrtf(ss) / (1.f + ss);
            *reinterpret_cast<float2*>(&sact_f[w * 164 + 2 * l]) = make_float2(a0 * sc, a1 * sc);
            if (l < 16) {
                const int od1 = 8 + (l >> 3);
                float c0 = b1.x, c1 = b1.y;
#pragma unroll
                for (int i = 0; i < NI; ++i) {
                    const unsigned d = *reinterpret_cast<const unsigned*>(&sv[w][i][128 + 2 * l]);
                    const float r = srt_f[(w * NOD + od1) * 33 + i];
                    c0 = fmaf(r, bf_lo(d), c0);
                    c1 = fmaf(r, bf_hi(d), c1);
                }
                float s2 = c0 * c0 + c1 * c1;
                s2 += __shfl_xor(s2, 1, 8);
                s2 += __shfl_xor(s2, 2, 8);
                s2 += __shfl_xor(s2, 4, 8);
                const float sc2 = sqrtf(s2) / (1.f + s2);
                *reinterpret_cast<float2*>(&sact_f[w * 164 + 128 + 2 * l]) =
                    make_float2(c0 * sc2, c1 * sc2);
            }
        }
        __builtin_amdgcn_wave_barrier();
        if (it < NROUT - 1) {
#pragma unroll
            for (int r = 0; r < 5; ++r) {
                const int t  = l + 64 * r;
                const int i  = t & 31;
                const int od = t >> 5;
                const uint4 d0 = *reinterpret_cast<const uint4*>(&sv[w][i][od * NOA]);
                const uint4 d1 = *reinterpret_cast<const uint4*>(&sv[w][i][od * NOA + 8]);
                const float* ap = &sact_f[w * 164 + od * NOA];
                const float4 c0 = *reinterpret_cast<const float4*>(ap + 0);
                const float4 c1 = *reinterpret_cast<const float4*>(ap + 4);
                const float4 c2 = *reinterpret_cast<const float4*>(ap + 8);
                const float4 c3 = *reinterpret_cast<const float4*>(ap + 12);
                float acc;
                acc  = bf_lo(d0.x) * c0.x;
                acc = fmaf(bf_hi(d0.x), c0.y, acc);
                acc = fmaf(bf_lo(d0.y), c0.z, acc);
                acc = fmaf(bf_hi(d0.y), c0.w, acc);
                acc = fmaf(bf_lo(d0.z), c1.x, acc);
                acc = fmaf(bf_hi(d0.z), c1.y, acc);
                acc = fmaf(bf_lo(d0.w), c1.z, acc);
                acc = fmaf(bf_hi(d0.w), c1.w, acc);
                acc = fmaf(bf_lo(d1.x), c2.x, acc);
                acc = fmaf(bf_hi(d1.x), c2.y, acc);
                acc = fmaf(bf_lo(d1.y), c2.z, acc);
                acc = fmaf(bf_hi(d1.y), c2.w, acc);
                acc = fmaf(bf_lo(d1.z), c3.x, acc);
                acc = fmaf(bf_hi(d1.z), c3.y, acc);
                acc = fmaf(bf_lo(d1.w), c3.z, acc);
                acc = fmaf(bf_hi(d1.w), c3.w, acc);
                srt_f[(w * NOD + od) * 33 + i] = acc;
            }
            __builtin_amdgcn_wave_barrier();
#pragma unroll
            for (int od = 0; od < NOD; ++od)
                lg[od] += srt_f[(w * NOD + od) * 33 + iown];
            __builtin_amdgcn_wave_barrier();
        }
    }

    __syncthreads();
    if (tid < NK) {
        const float4 v = make_float4(sact_f[0 * 164 + tid], sact_f[1 * 164 + tid],
                                     sact_f[2 * 164 + tid], sact_f[3 * 164 + tid]);
        *reinterpret_cast<float4*>(out + ((size_t)b * NK + tid) * NHW + hw0) = v;
    }
}

extern "C" void kernel_launch(void* const* d_in, const int* in_sizes, int n_in,
                              void* d_out, int out_size, void* d_ws, size_t ws_size,
                              hipStream_t stream) {
    const float* x      = (const float*)d_in[0];
    const float* weight = (const float*)d_in[1];
    const float* bias   = (const float*)d_in[2];
    float* out          = (float*)d_out;

    if (ws_size >= WS_NEEDED) {
        unsigned short* w_bf = (unsigned short*)d_ws;
        float* x_t = (float*)((char*)d_ws + XT_OFF);
        prepass_kernel<<<320 + NB * 72, 256, 0, stream>>>(x, weight, w_bf, x_t);
        capsule_fused3_kernel<<<NROWS / 4, 256, 0, stream>>>(x_t, w_bf, bias, out);
    } else {
        capsule_fused_kernel<<<NROWS / 4, 256, 0, stream>>>(x, weight, bias, out);
    }
}